// Round 3
// baseline (19548.445 us; speedup 1.0000x reference)
//
#include <hip/hip_runtime.h>

typedef _Float16 f16;
typedef _Float16 f16x8 __attribute__((ext_vector_type(8)));
typedef float    f32x4 __attribute__((ext_vector_type(4)));

#define NSTEP 2048
#define HID   512
#define BATCH 32
#define SEQL  2048

// ---------------------------------------------------------------------------
// Phase 1: xproj[m][n] = sum_k x[m][k] * Wxh[n][k] + (bxh+bhh+bh)[n], f16 out
// (unchanged from R1/R2)
// ---------------------------------------------------------------------------
#define P1_AS 40

__global__ __launch_bounds__(256, 2) void xproj_kernel(
    const float* __restrict__ x, const float* __restrict__ Wxh,
    const float* __restrict__ bxh, const float* __restrict__ bhh,
    const float* __restrict__ bh, f16* __restrict__ xp)
{
    __shared__ __align__(16) f16 As[64 * P1_AS];
    __shared__ __align__(16) f16 Bs[512 * P1_AS];

    const int t = threadIdx.x;
    const int wave = t >> 6, lane = t & 63;
    const size_t mbase = (size_t)blockIdx.x * 64;

    f32x4 acc[4][8];
#pragma unroll
    for (int i = 0; i < 4; i++)
#pragma unroll
        for (int j = 0; j < 8; j++) acc[i][j] = (f32x4){0.f, 0.f, 0.f, 0.f};

    const int r_st = t >> 2;
    const int koff = (t & 3) * 8;

    for (int k0 = 0; k0 < 512; k0 += 32) {
        __syncthreads();
        {
            const float* src = x + (mbase + r_st) * 512 + k0 + koff;
            float4 a0 = *(const float4*)src;
            float4 a1 = *(const float4*)(src + 4);
            f16x8 h;
            h[0] = (f16)a0.x; h[1] = (f16)a0.y; h[2] = (f16)a0.z; h[3] = (f16)a0.w;
            h[4] = (f16)a1.x; h[5] = (f16)a1.y; h[6] = (f16)a1.z; h[7] = (f16)a1.w;
            *(f16x8*)&As[r_st * P1_AS + koff] = h;
        }
#pragma unroll
        for (int i = 0; i < 8; i++) {
            int n = r_st + i * 64;
            const float* src = Wxh + (size_t)n * 512 + k0 + koff;
            float4 b0 = *(const float4*)src;
            float4 b1 = *(const float4*)(src + 4);
            f16x8 h;
            h[0] = (f16)b0.x; h[1] = (f16)b0.y; h[2] = (f16)b0.z; h[3] = (f16)b0.w;
            h[4] = (f16)b1.x; h[5] = (f16)b1.y; h[6] = (f16)b1.z; h[7] = (f16)b1.w;
            *(f16x8*)&Bs[n * P1_AS + koff] = h;
        }
        __syncthreads();

        f16x8 af[4];
#pragma unroll
        for (int rt = 0; rt < 4; rt++)
            af[rt] = *(const f16x8*)&As[(rt * 16 + (lane & 15)) * P1_AS + (lane >> 4) * 8];
#pragma unroll
        for (int ct = 0; ct < 8; ct++) {
            f16x8 bf = *(const f16x8*)&Bs[((wave * 8 + ct) * 16 + (lane & 15)) * P1_AS + (lane >> 4) * 8];
#pragma unroll
            for (int rt = 0; rt < 4; rt++)
                acc[rt][ct] = __builtin_amdgcn_mfma_f32_16x16x32_f16(af[rt], bf, acc[rt][ct], 0, 0, 0);
        }
    }

#pragma unroll
    for (int ct = 0; ct < 8; ct++) {
        int n = wave * 128 + ct * 16 + (lane & 15);
        float bias = bxh[n] + bhh[n] + bh[n];
#pragma unroll
        for (int rt = 0; rt < 4; rt++) {
#pragma unroll
            for (int r = 0; r < 4; r++) {
                size_t m = mbase + rt * 16 + (lane >> 4) * 4 + r;
                xp[m * 512 + n] = (f16)(acc[rt][ct][r] + bias);
            }
        }
    }
}

// ---------------------------------------------------------------------------
// Phase 2: recurrence, 2 CUs per batch (64 blocks x 256 thr, 1 wave/SIMD).
// Block (b, p=half) owns output cols [p*256, p*256+256).  W slice is 100%
// register-resident: 4 N-tiles/wave x 16 kf x f16x8 = 256 VGPRs (R2 showed
// the old design was LDS-pipe bound: 256 ds_read_b128/step/CU ~= 3072 cyc
// ~= the measured 2870 cyc/step; W-in-LDS is structurally >=128KiB/step).
// Own-half h via small LDS buffer (32 b128 reads/step/CU); partner half via
// L2 (global hx, parity double-buffered, per-wave flags == step counter —
// equality polling is 0xAA-poison-safe; partner can't overwrite parity slot
// until it passes OUR flag, which we publish only after consuming its data).
// wreg[t][i] holds global kf = (p*8+i)&15 so compute indices are constant:
// i in [0,8) = own k-range, [8,16) = partner k-range.
// ---------------------------------------------------------------------------
__global__ __launch_bounds__(256, 1) void rnn_kernel(
    const float* __restrict__ Whh, const f16* __restrict__ xp,
    f16* __restrict__ hx, int* __restrict__ flags, f16* __restrict__ hfin)
{
    __shared__ __align__(16) f16 hbuf[2][256];

    const int t = threadIdx.x;
    const int wave = t >> 6, lane = t & 63;
    const int b = blockIdx.x & 31;
    const int p = blockIdx.x >> 5;           // half: 0 or 1

    const int c_in = lane & 15;
    const int k8   = (lane >> 4) * 8;
    const int nloc = wave * 64 + (lane >> 4) * 16 + (lane & 15);  // 0..255
    const int ngbl = p * 256 + nloc;

    // ---- W_hh fragments, all-register.  wreg[t][i]: global kf=(p*8+i)&15 ----
    f16x8 wreg[4][16];
#pragma unroll
    for (int tt = 0; tt < 4; tt++) {
        const float* wrow = Whh + (size_t)((p * 16 + wave * 4 + tt) * 16 + c_in) * 512;
#pragma unroll
        for (int i = 0; i < 16; i++) {
            int kg = (((p * 8 + i) & 15) * 32 + k8);
            float4 w0 = *(const float4*)(wrow + kg);
            float4 w1 = *(const float4*)(wrow + kg + 4);
            f16x8 h;
            h[0] = (f16)w0.x; h[1] = (f16)w0.y; h[2] = (f16)w0.z; h[3] = (f16)w0.w;
            h[4] = (f16)w1.x; h[5] = (f16)w1.y; h[6] = (f16)w1.z; h[7] = (f16)w1.w;
            wreg[tt][i] = h;
        }
    }

    const f16* xprow = xp + (size_t)b * SEQL * 512 + ngbl;
    const int  pb_base = ((b * 2 + (1 - p)) * 2);   // partner hx/flag group
    const int  my_base = ((b * 2 + p) * 2);

    float xv = (float)xprow[0];
    f16 hn = (f16)0.f;

    for (int s = 0; s < NSTEP; s++) {
        int sn = (s + 1 < NSTEP) ? s + 1 : s;
        float xv_next = (float)xprow[(size_t)sn * 512];

        float v;
        if (s > 0) {
            f32x4 a0 = (f32x4){0.f,0.f,0.f,0.f}, a1 = a0, a2 = a0, a3 = a0;

            // poll partner flags (4 waves) == s, then its 256 h from L2
            const int* pf = flags + (pb_base + (s & 1)) * 4;
            int fv;
            do {
                fv = __hip_atomic_load(&pf[lane & 3], __ATOMIC_RELAXED,
                                       __HIP_MEMORY_SCOPE_AGENT);
            } while (__any(fv != s));
            __threadfence();

            const f16* ph = hx + (pb_base + (s & 1)) * 256;
            f16x8 pv[8];
#pragma unroll
            for (int i = 0; i < 8; i++)
                pv[i] = *(const f16x8*)&ph[i * 32 + k8];

            // own-half k (A from LDS; VMEM latency for pv hides under this)
            const f16* hb = hbuf[s & 1];
#pragma unroll
            for (int i = 0; i < 8; i++) {
                f16x8 av = *(const f16x8*)&hb[i * 32 + k8];
                a0 = __builtin_amdgcn_mfma_f32_16x16x32_f16(av, wreg[0][i], a0, 0, 0, 0);
                a1 = __builtin_amdgcn_mfma_f32_16x16x32_f16(av, wreg[1][i], a1, 0, 0, 0);
                a2 = __builtin_amdgcn_mfma_f32_16x16x32_f16(av, wreg[2][i], a2, 0, 0, 0);
                a3 = __builtin_amdgcn_mfma_f32_16x16x32_f16(av, wreg[3][i], a3, 0, 0, 0);
            }
            // partner-half k
#pragma unroll
            for (int i = 0; i < 8; i++) {
                a0 = __builtin_amdgcn_mfma_f32_16x16x32_f16(pv[i], wreg[0][8 + i], a0, 0, 0, 0);
                a1 = __builtin_amdgcn_mfma_f32_16x16x32_f16(pv[i], wreg[1][8 + i], a1, 0, 0, 0);
                a2 = __builtin_amdgcn_mfma_f32_16x16x32_f16(pv[i], wreg[2][8 + i], a2, 0, 0, 0);
                a3 = __builtin_amdgcn_mfma_f32_16x16x32_f16(pv[i], wreg[3][8 + i], a3, 0, 0, 0);
            }
            // D: col=lane&15 (all 4 rows equal, broadcast A) -> lane owns
            // tile jt=lane>>4, col lane&15, reg 0
            int jt = lane >> 4;
            float a = (jt == 0) ? a0[0] : (jt == 1) ? a1[0] : (jt == 2) ? a2[0] : a3[0];
            v = a + xv;
        } else {
            v = xv;                          // h0 = 0
        }
        float e = __expf(2.f * v);
        v = 1.f - 2.f / (e + 1.f);           // tanh, saturating, no NaN
        hn = (f16)v;

        int par1 = (s + 1) & 1;
        hbuf[par1][nloc] = hn;               // own half for next step's A
        hx[(my_base + par1) * 256 + nloc] = hn;  // publish to partner
        __threadfence();
        if (lane == 0)
            __hip_atomic_store(&flags[(my_base + par1) * 4 + wave], s + 1,
                               __ATOMIC_RELAXED, __HIP_MEMORY_SCOPE_AGENT);
        xv = xv_next;
        __syncthreads();
    }

    hfin[(size_t)b * 512 + ngbl] = hn;       // final h^NSTEP
}

// ---------------------------------------------------------------------------
// Phase 3: out[b][o] = sum_k h[b][k] * Wfc[o][k] + bfc[o]  (unchanged)
// ---------------------------------------------------------------------------
#define P3_HS 520

__global__ __launch_bounds__(256, 2) void fc_kernel(
    const f16* __restrict__ hfin, const float* __restrict__ Wfc,
    const float* __restrict__ bfc, float* __restrict__ out)
{
    __shared__ __align__(16) f16 hs[BATCH * P3_HS];
    const int t = threadIdx.x;
    for (int i = 0; i < 64; i++) {
        int e = i * 256 + t;
        hs[(e >> 9) * P3_HS + (e & 511)] = hfin[e];
    }
    __syncthreads();

    const int bidx = t & 31;
    const int oi = t >> 5;
    const int o0 = blockIdx.x * 16;
    const int oA = o0 + oi, oB = o0 + oi + 8;
    const float* wA = Wfc + (size_t)oA * 512;
    const float* wB = Wfc + (size_t)oB * 512;

    float sA = 0.f, sB = 0.f;
#pragma unroll 4
    for (int kb = 0; kb < 64; kb++) {
        f16x8 hv = *(const f16x8*)&hs[bidx * P3_HS + kb * 8];
        float4 wa0 = *(const float4*)(wA + kb * 8);
        float4 wa1 = *(const float4*)(wA + kb * 8 + 4);
        float4 wb0 = *(const float4*)(wB + kb * 8);
        float4 wb1 = *(const float4*)(wB + kb * 8 + 4);
        float h0 = (float)hv[0], h1 = (float)hv[1], h2 = (float)hv[2], h3 = (float)hv[3];
        float h4 = (float)hv[4], h5 = (float)hv[5], h6 = (float)hv[6], h7 = (float)hv[7];
        sA += wa0.x*h0 + wa0.y*h1 + wa0.z*h2 + wa0.w*h3 + wa1.x*h4 + wa1.y*h5 + wa1.z*h6 + wa1.w*h7;
        sB += wb0.x*h0 + wb0.y*h1 + wb0.z*h2 + wb0.w*h3 + wb1.x*h4 + wb1.y*h5 + wb1.z*h6 + wb1.w*h7;
    }
    out[(size_t)bidx * 512 + oA] = sA + bfc[oA];
    out[(size_t)bidx * 512 + oB] = sB + bfc[oB];
}

// ---------------------------------------------------------------------------
extern "C" void kernel_launch(void* const* d_in, const int* in_sizes, int n_in,
                              void* d_out, int out_size, void* d_ws, size_t ws_size,
                              hipStream_t stream) {
    const float* x    = (const float*)d_in[0];
    const float* Wxh  = (const float*)d_in[1];
    const float* bxh  = (const float*)d_in[2];
    const float* Whh  = (const float*)d_in[3];
    const float* bhh  = (const float*)d_in[4];
    const float* bh   = (const float*)d_in[5];
    const float* Wfc  = (const float*)d_in[6];
    const float* bfc  = (const float*)d_in[7];
    float* outp = (float*)d_out;

    char* ws = (char*)d_ws;
    f16* xp   = (f16*)ws;                                   // 64 MiB
    f16* hfin = (f16*)(ws + (size_t)BATCH * SEQL * 512 * 2);         // 32 KiB
    f16* hx   = (f16*)(ws + (size_t)BATCH * SEQL * 512 * 2 + 32768); // 64 KiB
    int* flags = (int*)(ws + (size_t)BATCH * SEQL * 512 * 2 + 32768 + 65536);

    xproj_kernel<<<(BATCH * SEQL) / 64, 256, 0, stream>>>(x, Wxh, bxh, bhh, bh, xp);
    rnn_kernel<<<64, 256, 0, stream>>>(Whh, xp, hx, flags, hfin);
    fc_kernel<<<32, 256, 0, stream>>>(hfin, Wfc, bfc, outp);
}

// Round 5
// 8370.462 us; speedup vs baseline: 2.3354x; 2.3354x over previous
//
#include <hip/hip_runtime.h>

typedef _Float16 f16;
typedef _Float16 f16x2 __attribute__((ext_vector_type(2)));
typedef _Float16 f16x8 __attribute__((ext_vector_type(8)));
typedef float    f32x4 __attribute__((ext_vector_type(4)));

#define NSTEP 2048
#define HID   512
#define BATCH 32
#define SEQL  2048

// ---------------------------------------------------------------------------
// Phase 1: xproj[m][n] = sum_k x[m][k] * Wxh[n][k] + (bxh+bhh+bh)[n], f16 out
// (unchanged — revisit once rnn is at its floor)
// ---------------------------------------------------------------------------
#define P1_AS 40

__global__ __launch_bounds__(256, 2) void xproj_kernel(
    const float* __restrict__ x, const float* __restrict__ Wxh,
    const float* __restrict__ bxh, const float* __restrict__ bhh,
    const float* __restrict__ bh, f16* __restrict__ xp)
{
    __shared__ __align__(16) f16 As[64 * P1_AS];
    __shared__ __align__(16) f16 Bs[512 * P1_AS];

    const int t = threadIdx.x;
    const int wave = t >> 6, lane = t & 63;
    const size_t mbase = (size_t)blockIdx.x * 64;

    f32x4 acc[4][8];
#pragma unroll
    for (int i = 0; i < 4; i++)
#pragma unroll
        for (int j = 0; j < 8; j++) acc[i][j] = (f32x4){0.f, 0.f, 0.f, 0.f};

    const int r_st = t >> 2;
    const int koff = (t & 3) * 8;

    for (int k0 = 0; k0 < 512; k0 += 32) {
        __syncthreads();
        {
            const float* src = x + (mbase + r_st) * 512 + k0 + koff;
            float4 a0 = *(const float4*)src;
            float4 a1 = *(const float4*)(src + 4);
            f16x8 h;
            h[0] = (f16)a0.x; h[1] = (f16)a0.y; h[2] = (f16)a0.z; h[3] = (f16)a0.w;
            h[4] = (f16)a1.x; h[5] = (f16)a1.y; h[6] = (f16)a1.z; h[7] = (f16)a1.w;
            *(f16x8*)&As[r_st * P1_AS + koff] = h;
        }
#pragma unroll
        for (int i = 0; i < 8; i++) {
            int n = r_st + i * 64;
            const float* src = Wxh + (size_t)n * 512 + k0 + koff;
            float4 b0 = *(const float4*)src;
            float4 b1 = *(const float4*)(src + 4);
            f16x8 h;
            h[0] = (f16)b0.x; h[1] = (f16)b0.y; h[2] = (f16)b0.z; h[3] = (f16)b0.w;
            h[4] = (f16)b1.x; h[5] = (f16)b1.y; h[6] = (f16)b1.z; h[7] = (f16)b1.w;
            *(f16x8*)&Bs[n * P1_AS + koff] = h;
        }
        __syncthreads();

        f16x8 af[4];
#pragma unroll
        for (int rt = 0; rt < 4; rt++)
            af[rt] = *(const f16x8*)&As[(rt * 16 + (lane & 15)) * P1_AS + (lane >> 4) * 8];
#pragma unroll
        for (int ct = 0; ct < 8; ct++) {
            f16x8 bf = *(const f16x8*)&Bs[((wave * 8 + ct) * 16 + (lane & 15)) * P1_AS + (lane >> 4) * 8];
#pragma unroll
            for (int rt = 0; rt < 4; rt++)
                acc[rt][ct] = __builtin_amdgcn_mfma_f32_16x16x32_f16(af[rt], bf, acc[rt][ct], 0, 0, 0);
        }
    }

#pragma unroll
    for (int ct = 0; ct < 8; ct++) {
        int n = wave * 128 + ct * 16 + (lane & 15);
        float bias = bxh[n] + bhh[n] + bh[n];
#pragma unroll
        for (int rt = 0; rt < 4; rt++) {
#pragma unroll
            for (int r = 0; r < 4; r++) {
                size_t m = mbase + rt * 16 + (lane >> 4) * 4 + r;
                xp[m * 512 + n] = (f16)(acc[rt][ct][r] + bias);
            }
        }
    }
}

// ---------------------------------------------------------------------------
// Phase 2: recurrence, 1 CU/batch, dot2-based (no MFMA: its A-fragment
// replication makes the LDS pipe a 2870cyc/step floor — R2).
// Lane owns output n = threadIdx.x.  W[n][k]: 208 f16x2 pairs in VGPRs
// (k<416) + 48 pairs in LDS (12 ds_read_b128/lane/step; ~1152cyc/CU ~= the
// VALU floor ~1100cyc; R4's 192/64 split would be LDS-bound at 1536).
// h is wave-uniform: broadcast 16B global loads (1 req/instr, same-CU
// coherent through L1; R4's partial-correctness proves this mechanism).
// h double-buffered in global ws; __syncthreads' vmcnt(0) drain publishes.
// R4 BUG FIXED: tail now covers ALL k in [416,512) — hp[52..63] paired with
// 48 LDS W pairs (R4 silently dropped k in [448,512) -> absmax 0.2).
// ---------------------------------------------------------------------------
#define REGP   208             // pairs per lane in VGPRs  (k in [0,416))
#define TAILP  48              // pairs per lane from LDS  (k in [416,512))
#define TSTR   52              // tail row stride in f16x2 (208B: 16B-aligned,
                               // dword stride 20 mod 32 -> 2-way banks = free)
#define P2_LDS_BYTES (HID * TSTR * 4)   // 106496 B

__global__ __launch_bounds__(512) void rnn_kernel(
    const float* __restrict__ Whh, const f16* __restrict__ xp,
    f16* __restrict__ hx, f16* __restrict__ hfin)
{
    extern __shared__ __align__(16) char smem[];
    f16x2* tail = (f16x2*)smem;          // [n * TSTR + j], j in [0,48)

    const int t = threadIdx.x;
    const int b = blockIdx.x;
    const int n = t;                     // lane's output index, 0..511

    // ---- load W row n: 208 pairs -> VGPRs, 48 pairs -> LDS ----
    const float4* wrow4 = (const float4*)(Whh + (size_t)n * 512);
    f16x2 wreg[REGP];
#pragma unroll
    for (int j4 = 0; j4 < REGP / 2; j4++) {       // 104 float4 = 208 pairs
        float4 w = wrow4[j4];
        f16x2 p0; p0[0] = (f16)w.x; p0[1] = (f16)w.y;
        f16x2 p1; p1[0] = (f16)w.z; p1[1] = (f16)w.w;
        wreg[2 * j4]     = p0;
        wreg[2 * j4 + 1] = p1;
    }
#pragma unroll
    for (int j4 = 0; j4 < TAILP / 2; j4++) {      // 24 float4 = 48 pairs
        float4 w = wrow4[REGP / 2 + j4];
        f16x2 p0; p0[0] = (f16)w.x; p0[1] = (f16)w.y;
        f16x2 p1; p1[0] = (f16)w.z; p1[1] = (f16)w.w;
        tail[n * TSTR + 2 * j4]     = p0;
        tail[n * TSTR + 2 * j4 + 1] = p1;
    }
    __syncthreads();

    // opaque divergent zero: keeps the broadcast address in VGPRs so the
    // compiler can't scalarize the load into the (non-coherent) scalar cache
    int zoff;
    asm volatile("v_mov_b32 %0, 0" : "=v"(zoff));

    const f16* xprow = xp + (size_t)b * SEQL * 512 + n;
    f16* hx0 = hx + (size_t)b * 2 * HID;             // parity buffers

    float xv = (float)xprow[0];
    f16 hn = (f16)0.f;

    for (int s = 0; s < NSTEP; s++) {
        int sn = (s + 1 < NSTEP) ? s + 1 : s;
        float xv_next = (float)xprow[(size_t)sn * 512];

        float v;
        if (s > 0) {
            const float4* hp = (const float4*)((const char*)(hx0 + (s & 1) * HID) + zoff);
            float a0 = 0.f, a1 = 0.f, a2 = 0.f, a3 = 0.f;
            // k < 416: W from VGPRs, h via broadcast 16B loads (4 pairs each)
#pragma unroll
            for (int j = 0; j < REGP / 4; j++) {     // 52 iters
                float4 hv = hp[j];
                f16x2 p0 = ((const f16x2*)&hv)[0];
                f16x2 p1 = ((const f16x2*)&hv)[1];
                f16x2 p2 = ((const f16x2*)&hv)[2];
                f16x2 p3 = ((const f16x2*)&hv)[3];
                a0 = __builtin_amdgcn_fdot2(wreg[4 * j + 0], p0, a0, false);
                a1 = __builtin_amdgcn_fdot2(wreg[4 * j + 1], p1, a1, false);
                a2 = __builtin_amdgcn_fdot2(wreg[4 * j + 2], p2, a2, false);
                a3 = __builtin_amdgcn_fdot2(wreg[4 * j + 3], p3, a3, false);
            }
            // k in [416,512): W streamed from LDS (12 x ds_read_b128)
#pragma unroll
            for (int j2 = 0; j2 < TAILP / 4; j2++) { // 12 iters
                float4 hv = hp[REGP / 4 + j2];
                f16x8 tv = *(const f16x8*)&tail[n * TSTR + 4 * j2];
                f16x2 q0 = ((const f16x2*)&tv)[0];
                f16x2 q1 = ((const f16x2*)&tv)[1];
                f16x2 q2 = ((const f16x2*)&tv)[2];
                f16x2 q3 = ((const f16x2*)&tv)[3];
                f16x2 p0 = ((const f16x2*)&hv)[0];
                f16x2 p1 = ((const f16x2*)&hv)[1];
                f16x2 p2 = ((const f16x2*)&hv)[2];
                f16x2 p3 = ((const f16x2*)&hv)[3];
                a0 = __builtin_amdgcn_fdot2(q0, p0, a0, false);
                a1 = __builtin_amdgcn_fdot2(q1, p1, a1, false);
                a2 = __builtin_amdgcn_fdot2(q2, p2, a2, false);
                a3 = __builtin_amdgcn_fdot2(q3, p3, a3, false);
            }
            v = (a0 + a1) + (a2 + a3) + xv;
        } else {
            v = xv;                      // h0 = 0
        }
        float e = __expf(2.f * v);
        v = 1.f - 2.f / (e + 1.f);       // tanh, saturating, no NaN
        hn = (f16)v;

        hx0[((s + 1) & 1) * HID + n] = hn;   // publish for next step
        xv = xv_next;
        __syncthreads();                 // vmcnt(0) drain -> stores visible
    }

    hfin[(size_t)b * 512 + n] = hn;
}

// ---------------------------------------------------------------------------
// Phase 3: out[b][o] = sum_k h[b][k] * Wfc[o][k] + bfc[o]  (unchanged)
// ---------------------------------------------------------------------------
#define P3_HS 520

__global__ __launch_bounds__(256, 2) void fc_kernel(
    const f16* __restrict__ hfin, const float* __restrict__ Wfc,
    const float* __restrict__ bfc, float* __restrict__ out)
{
    __shared__ __align__(16) f16 hs[BATCH * P3_HS];
    const int t = threadIdx.x;
    for (int i = 0; i < 64; i++) {
        int e = i * 256 + t;
        hs[(e >> 9) * P3_HS + (e & 511)] = hfin[e];
    }
    __syncthreads();

    const int bidx = t & 31;
    const int oi = t >> 5;
    const int o0 = blockIdx.x * 16;
    const int oA = o0 + oi, oB = o0 + oi + 8;
    const float* wA = Wfc + (size_t)oA * 512;
    const float* wB = Wfc + (size_t)oB * 512;

    float sA = 0.f, sB = 0.f;
#pragma unroll 4
    for (int kb = 0; kb < 64; kb++) {
        f16x8 hv = *(const f16x8*)&hs[bidx * P3_HS + kb * 8];
        float4 wa0 = *(const float4*)(wA + kb * 8);
        float4 wa1 = *(const float4*)(wA + kb * 8 + 4);
        float4 wb0 = *(const float4*)(wB + kb * 8);
        float4 wb1 = *(const float4*)(wB + kb * 8 + 4);
        float h0 = (float)hv[0], h1 = (float)hv[1], h2 = (float)hv[2], h3 = (float)hv[3];
        float h4 = (float)hv[4], h5 = (float)hv[5], h6 = (float)hv[6], h7 = (float)hv[7];
        sA += wa0.x*h0 + wa0.y*h1 + wa0.z*h2 + wa0.w*h3 + wa1.x*h4 + wa1.y*h5 + wa1.z*h6 + wa1.w*h7;
        sB += wb0.x*h0 + wb0.y*h1 + wb0.z*h2 + wb0.w*h3 + wb1.x*h4 + wb1.y*h5 + wb1.z*h6 + wb1.w*h7;
    }
    out[(size_t)bidx * 512 + oA] = sA + bfc[oA];
    out[(size_t)bidx * 512 + oB] = sB + bfc[oB];
}

// ---------------------------------------------------------------------------
extern "C" void kernel_launch(void* const* d_in, const int* in_sizes, int n_in,
                              void* d_out, int out_size, void* d_ws, size_t ws_size,
                              hipStream_t stream) {
    const float* x    = (const float*)d_in[0];
    const float* Wxh  = (const float*)d_in[1];
    const float* bxh  = (const float*)d_in[2];
    const float* Whh  = (const float*)d_in[3];
    const float* bhh  = (const float*)d_in[4];
    const float* bh   = (const float*)d_in[5];
    const float* Wfc  = (const float*)d_in[6];
    const float* bfc  = (const float*)d_in[7];
    float* outp = (float*)d_out;

    char* ws = (char*)d_ws;
    f16* xp   = (f16*)ws;                                        // 64 MiB
    f16* hfin = (f16*)(ws + (size_t)BATCH * SEQL * 512 * 2);     // 32 KiB
    f16* hx   = (f16*)(ws + (size_t)BATCH * SEQL * 512 * 2 + 32768); // 64 KiB

    hipFuncSetAttribute((const void*)rnn_kernel,
                        hipFuncAttributeMaxDynamicSharedMemorySize, 160 * 1024);

    xproj_kernel<<<(BATCH * SEQL) / 64, 256, 0, stream>>>(x, Wxh, bxh, bhh, bh, xp);
    rnn_kernel<<<BATCH, 512, P2_LDS_BYTES, stream>>>(Whh, xp, hx, hfin);
    fc_kernel<<<32, 256, 0, stream>>>(hfin, Wfc, bfc, outp);
}